// Round 4
// baseline (108.360 us; speedup 1.0000x reference)
//
#include <hip/hip_runtime.h>

#define BB 64
#define TT 512
#define DD 768
#define LL 5
#define NSEQ 128
#define NTOK 65536
#define NEG_INF (-1e30f)
#define IDENT_W 0x4688u   // bp word encoding j->j (0|1<<3|2<<6|3<<9|4<<12)

// ---------------------------------------------------------------------------
// Kernel A: logits = x @ W + b. One thread per token. W read via wave-uniform
// scalar loads (s_load through constant cache) — no LDS at all. Tokens with
// t >= seqlen are never consumed downstream -> early exit (saves ~50% of the
// 201 MB x read). Each block covers half of one sequence => sl block-uniform.
// ---------------------------------------------------------------------------
__global__ __launch_bounds__(256) void k_logits(const float* __restrict__ x,
                                                const float* __restrict__ W,
                                                const float* __restrict__ bias,
                                                const int* __restrict__ seqlen,
                                                float* __restrict__ logits) {
    const int tok = blockIdx.x * 256 + threadIdx.x;   // grid 256 -> exact cover
    const int t   = tok & (TT - 1);
    const int n   = tok >> 9;
    const int sl  = seqlen[n & (BB - 1)];
    if (t >= sl) return;                              // block-uniform exit

    const float4* xp = reinterpret_cast<const float4*>(x + (size_t)tok * DD);
    float a0 = 0.f, a1 = 0.f, a2 = 0.f, a3 = 0.f, a4 = 0.f;
#pragma unroll 8
    for (int q = 0; q < DD / 4; ++q) {
        const float4 v = xp[q];
        const float* w = W + q * 4 * LL;              // uniform address -> SGPR
        a0 += v.x * w[0] + v.y * w[5] + v.z * w[10] + v.w * w[15];
        a1 += v.x * w[1] + v.y * w[6] + v.z * w[11] + v.w * w[16];
        a2 += v.x * w[2] + v.y * w[7] + v.z * w[12] + v.w * w[17];
        a3 += v.x * w[3] + v.y * w[8] + v.z * w[13] + v.w * w[18];
        a4 += v.x * w[4] + v.y * w[9] + v.z * w[14] + v.w * w[19];
    }
    float* o = logits + (size_t)tok * LL;
    o[0] = a0 + bias[0];
    o[1] = a1 + bias[1];
    o[2] = a2 + bias[2];
    o[3] = a3 + bias[3];
    o[4] = a4 + bias[4];
}

// ---------------------------------------------------------------------------
// Kernel B: chunked semiring scans + score.
// Blocks 0..127: log-norm (lse semiring); 128..255: viterbi (max-plus);
// 256..383: sequence score (parallel over t).
// ---------------------------------------------------------------------------
__global__ __launch_bounds__(256) void k_scan2(const float* __restrict__ logits,
                                               const int* __restrict__ label,
                                               const int* __restrict__ seqlen,
                                               const float* __restrict__ trans,
                                               float* __restrict__ lognorm,
                                               float* __restrict__ score,
                                               int* __restrict__ tags) {
    __shared__ float s_lg[TT * LL + 8];   // +pad: t=512 dummy reads
    __shared__ float s_P[32 * 25];
    __shared__ float s_A[33 * 5];
    __shared__ float s_tr[25];
    __shared__ float s_etr[25];
    __shared__ unsigned s_mapw[32];
    __shared__ int s_B[33];
    __shared__ int s_tags[TT];
    __shared__ float s_red[256];

    const int tid  = threadIdx.x;
    const int role = blockIdx.x >> 7;        // 0 = lognorm, 1 = viterbi, 2 = score
    const int n    = blockIdx.x & 127;
    const int sl   = seqlen[n & (BB - 1)];
    const float* lg = logits + (size_t)n * TT * LL;

    if (tid < 25) { const float tv = trans[tid]; s_tr[tid] = tv; s_etr[tid] = __expf(tv); }
    if (role < 2) {
        for (int i = tid; i < TT * LL + 8; i += 256)
            s_lg[i] = (i < TT * LL) ? lg[i] : 0.f;
    }
    __syncthreads();

    if (role == 0) {
        // ---------------- log-norm ----------------
        if (tid < 160) {
            const int c = tid / 5, r = tid - 5 * c;
            float p[5];
#pragma unroll
            for (int j = 0; j < 5; ++j) p[j] = (j == r) ? 0.f : NEG_INF;
#pragma unroll
            for (int i = 0; i < 16; ++i) {
                const int t = c * 16 + 1 + i;
                const bool act = t < sl;
                const float m = fmaxf(fmaxf(fmaxf(p[0], p[1]), fmaxf(p[2], p[3])), p[4]);
                float e[5];
#pragma unroll
                for (int k = 0; k < 5; ++k) e[k] = __expf(p[k] - m);
                float nv[5];
#pragma unroll
                for (int j = 0; j < 5; ++j) {
                    float s = e[0] * s_etr[j];
#pragma unroll
                    for (int k = 1; k < 5; ++k) s += e[k] * s_etr[k * 5 + j];
                    nv[j] = m + __logf(s) + s_lg[t * 5 + j];
                }
#pragma unroll
                for (int j = 0; j < 5; ++j) p[j] = act ? nv[j] : p[j];
            }
#pragma unroll
            for (int j = 0; j < 5; ++j) s_P[c * 25 + r * 5 + j] = __expf(p[j]);
        }
        __syncthreads();
        if (tid == 0) {
            float a[5];
#pragma unroll
            for (int j = 0; j < 5; ++j) a[j] = s_lg[j];
            for (int c = 0; c < 32; ++c) {
                const float m = fmaxf(fmaxf(fmaxf(a[0], a[1]), fmaxf(a[2], a[3])), a[4]);
                float e[5];
#pragma unroll
                for (int k = 0; k < 5; ++k) e[k] = __expf(a[k] - m);
                float nv[5];
#pragma unroll
                for (int j = 0; j < 5; ++j) {
                    float s = e[0] * s_P[c * 25 + j];
#pragma unroll
                    for (int k = 1; k < 5; ++k) s += e[k] * s_P[c * 25 + k * 5 + j];
                    nv[j] = m + __logf(s);
                }
#pragma unroll
                for (int j = 0; j < 5; ++j) a[j] = nv[j];
            }
            const float m = fmaxf(fmaxf(fmaxf(a[0], a[1]), fmaxf(a[2], a[3])), a[4]);
            float s = 0.f;
#pragma unroll
            for (int j = 0; j < 5; ++j) s += __expf(a[j] - m);
            lognorm[n] = m + __logf(s);
        }
    } else if (role == 1) {
        // ---------------- viterbi ----------------
        if (tid < 160) {
            const int c = tid / 5, r = tid - 5 * c;
            float p[5];
#pragma unroll
            for (int j = 0; j < 5; ++j) p[j] = (j == r) ? 0.f : NEG_INF;
#pragma unroll
            for (int i = 0; i < 16; ++i) {
                const int t = c * 16 + 1 + i;
                const bool act = t < sl;
                float nv[5];
#pragma unroll
                for (int j = 0; j < 5; ++j) {
                    float b = p[0] + s_tr[j];
#pragma unroll
                    for (int k = 1; k < 5; ++k) b = fmaxf(b, p[k] + s_tr[k * 5 + j]);
                    nv[j] = b + s_lg[t * 5 + j];
                }
#pragma unroll
                for (int j = 0; j < 5; ++j) p[j] = act ? nv[j] : p[j];
            }
#pragma unroll
            for (int j = 0; j < 5; ++j) s_P[c * 25 + r * 5 + j] = p[j];
        }
        __syncthreads();
        if (tid == 0) {                       // serial chunk-scan: boundary alphas
            float a[5];
#pragma unroll
            for (int j = 0; j < 5; ++j) { a[j] = s_lg[j]; s_A[j] = a[j]; }
            for (int c = 0; c < 32; ++c) {
                float nv[5];
#pragma unroll
                for (int j = 0; j < 5; ++j) {
                    float b = a[0] + s_P[c * 25 + j];
#pragma unroll
                    for (int k = 1; k < 5; ++k) b = fmaxf(b, a[k] + s_P[c * 25 + k * 5 + j]);
                    nv[j] = b;
                }
#pragma unroll
                for (int j = 0; j < 5; ++j) { a[j] = nv[j]; s_A[(c + 1) * 5 + j] = a[j]; }
            }
        }
        __syncthreads();
        unsigned bpw[16];                     // per-chunk backpointers, registers
        if (tid < 32) {
            const int c = tid;
            float a[5];
#pragma unroll
            for (int j = 0; j < 5; ++j) a[j] = s_A[c * 5 + j];
#pragma unroll
            for (int i = 0; i < 16; ++i) {
                const int t = c * 16 + 1 + i;
                const bool act = t < sl;
                float nv[5]; int gi[5];
#pragma unroll
                for (int j = 0; j < 5; ++j) {
                    float b = a[0] + s_tr[j]; int g = 0;
#pragma unroll
                    for (int k = 1; k < 5; ++k) {
                        const float cn = a[k] + s_tr[k * 5 + j];
                        if (cn > b) { b = cn; g = k; }
                    }
                    nv[j] = b + s_lg[t * 5 + j]; gi[j] = g;
                }
                const unsigned w = (unsigned)gi[0] | ((unsigned)gi[1] << 3) |
                                   ((unsigned)gi[2] << 6) | ((unsigned)gi[3] << 9) |
                                   ((unsigned)gi[4] << 12);
                bpw[i] = act ? w : IDENT_W;
#pragma unroll
                for (int j = 0; j < 5; ++j) a[j] = act ? nv[j] : a[j];
            }
            // compose chunk map (end-state -> start-state), pure VALU
            int m[5] = {0, 1, 2, 3, 4};
#pragma unroll
            for (int i = 15; i >= 0; --i) {
                const unsigned w = bpw[i];
#pragma unroll
                for (int j = 0; j < 5; ++j) m[j] = (int)((w >> (3 * m[j])) & 7u);
            }
            s_mapw[c] = (unsigned)m[0] | ((unsigned)m[1] << 3) | ((unsigned)m[2] << 6) |
                        ((unsigned)m[3] << 9) | ((unsigned)m[4] << 12);
        }
        __syncthreads();
        if (tid == 0) {                       // boundary tags via map chain (VALU)
            float b = s_A[32 * 5 + 0]; int lt = 0;
#pragma unroll
            for (int j = 1; j < 5; ++j) {
                const float cn = s_A[32 * 5 + j];
                if (cn > b) { b = cn; lt = j; }
            }
            unsigned w[32];
#pragma unroll
            for (int c = 0; c < 32; ++c) w[c] = s_mapw[c];
            int bc = lt; s_B[32] = lt;
#pragma unroll
            for (int c = 31; c >= 0; --c) { bc = (int)((w[c] >> (3 * bc)) & 7u); s_B[c] = bc; }
        }
        __syncthreads();
        if (tid < 32) {                       // emit tags from register bps
            int cur = s_B[tid + 1];
#pragma unroll
            for (int i = 15; i >= 0; --i) {
                cur = (int)((bpw[i] >> (3 * cur)) & 7u);
                s_tags[tid * 16 + i] = cur;
            }
        }
        __syncthreads();
        int* to = tags + n * TT;
        for (int i = tid; i < TT; i += 256) to[i] = s_tags[i];
    } else {
        // ---------------- sequence score ----------------
        const bool sec = (n >= BB);
        const int* lab = label + (n & (BB - 1)) * TT;
        float s = 0.f;
        for (int t = tid; t < TT; t += 256) {
            if (t < sl) {
                const int l = lab[t];
                const int tg = (l > 0) ? (sec ? l + 1 : 1) : 0;
                s += lg[t * LL + tg];
                if (t >= 1) {
                    const int lp = lab[t - 1];
                    const int tp = (lp > 0) ? (sec ? lp + 1 : 1) : 0;
                    s += s_tr[tp * LL + tg];
                }
            }
        }
        s_red[tid] = s;
        __syncthreads();
        for (int st = 128; st > 0; st >>= 1) {
            if (tid < st) s_red[tid] += s_red[tid + st];
            __syncthreads();
        }
        if (tid == 0) score[n] = s_red[0];
    }
}

// ---------------------------------------------------------------------------
// Kernel C: viterbi output + accuracy + loss, single block (replaces two
// kernels; all traffic L2-resident).
// ---------------------------------------------------------------------------
__global__ __launch_bounds__(1024) void k_tail(const int* __restrict__ tags,
                                               const int* __restrict__ label,
                                               const int* __restrict__ seqlen,
                                               const float* __restrict__ score,
                                               const float* __restrict__ lognorm,
                                               float* __restrict__ out) {
    __shared__ int s_ok[1024];
    __shared__ float s_f[1024];
    __shared__ int s_sl[1024];
    const int tid = threadIdx.x;
    int ok = 0;
    for (int i = tid; i < BB * TT; i += 1024) {
        const int bb = i >> 9, t = i & 511;
        const int v1 = tags[i];
        const int v2 = tags[i + BB * TT];
        const int vit = (v1 == 0 || v2 == 0) ? 0 : (v2 - 1);
        out[i] = (float)vit;
        ok += ((vit == label[i]) && (t < seqlen[bb])) ? 1 : 0;
    }
    s_ok[tid] = ok;
    s_f[tid]  = (tid < NSEQ) ? (lognorm[tid] - score[tid]) : 0.f;
    s_sl[tid] = (tid < BB) ? seqlen[tid] : 0;
    __syncthreads();
    for (int s = 512; s > 0; s >>= 1) {
        if (tid < s) { s_ok[tid] += s_ok[tid + s]; s_f[tid] += s_f[tid + s]; s_sl[tid] += s_sl[tid + s]; }
        __syncthreads();
    }
    if (tid == 0) {
        out[BB * TT]     = s_f[0] / (float)NSEQ;
        out[BB * TT + 1] = (float)s_ok[0] / (float)s_sl[0];
    }
}

// ---------------------------------------------------------------------------
extern "C" void kernel_launch(void* const* d_in, const int* in_sizes, int n_in,
                              void* d_out, int out_size, void* d_ws, size_t ws_size,
                              hipStream_t stream) {
    const float* x      = (const float*)d_in[0];
    const int*   label  = (const int*)d_in[1];
    const int*   seqlen = (const int*)d_in[2];
    const float* W      = (const float*)d_in[3];
    const float* bias   = (const float*)d_in[4];
    const float* trans  = (const float*)d_in[5];
    float* out = (float*)d_out;
    char*  ws  = (char*)d_ws;

    float* ws_logits  = (float*)(ws);                 // 1,310,720 B
    float* ws_score   = (float*)(ws + 1310720);       // 512 B
    float* ws_lognorm = (float*)(ws + 1311232);       // 512 B
    int*   ws_tags    = (int*)(ws + 1311744);         // 262,144 B

    hipLaunchKernelGGL(k_logits, dim3(256), dim3(256), 0, stream,
                       x, W, bias, seqlen, ws_logits);
    hipLaunchKernelGGL(k_scan2, dim3(384), dim3(256), 0, stream,
                       ws_logits, label, seqlen, trans, ws_lognorm, ws_score, ws_tags);
    hipLaunchKernelGGL(k_tail, dim3(1), dim3(1024), 0, stream,
                       ws_tags, label, seqlen, ws_score, ws_lognorm, out);
}

// Round 5
// 74.541 us; speedup vs baseline: 1.4537x; 1.4537x over previous
//
#include <hip/hip_runtime.h>

#define BB 64
#define TT 512
#define DD 768
#define LL 5
#define NSEQ 128
#define NTOK 65536
#define NEG_INF (-1e30f)
#define IDENT_W 0x4688u   // bp word encoding j->j (0|1<<3|2<<6|3<<9|4<<12)

// ---------------------------------------------------------------------------
// Kernel A: logits = x @ W + b. Wave-per-token (R1 structure, measured ~HBM
// floor): lane covers d = p*256 + lane*4 + q; W in per-lane registers
// (60 f32), x as coalesced float4 (1 KB/wave/instr), butterfly shuffle
// reduce. NEW: tokens with t >= seqlen are never consumed downstream ->
// wave-uniform skip (~50% of the 201 MB x read saved).
// ---------------------------------------------------------------------------
__global__ __launch_bounds__(256) void k_logits(const float* __restrict__ x,
                                                const float* __restrict__ W,
                                                const float* __restrict__ bias,
                                                const int* __restrict__ seqlen,
                                                float* __restrict__ logits) {
    const int lane = threadIdx.x & 63;
    const int wid  = blockIdx.x * (blockDim.x >> 6) + (threadIdx.x >> 6);
    const int nw   = gridDim.x * (blockDim.x >> 6);

    float wreg[3][4][LL];
#pragma unroll
    for (int p = 0; p < 3; ++p)
#pragma unroll
        for (int q = 0; q < 4; ++q) {
            const int d = p * 256 + lane * 4 + q;
#pragma unroll
            for (int l = 0; l < LL; ++l) wreg[p][q][l] = W[d * LL + l];
        }
    float breg[LL];
#pragma unroll
    for (int l = 0; l < LL; ++l) breg[l] = bias[l];

    for (int tok = wid; tok < NTOK; tok += nw) {
        const int t = tok & (TT - 1);
        const int n = tok >> 9;
        if (t >= seqlen[n & (BB - 1)]) continue;      // wave-uniform skip

        const float4* xp = reinterpret_cast<const float4*>(x + (size_t)tok * DD);
        float acc[LL] = {0.f, 0.f, 0.f, 0.f, 0.f};
#pragma unroll
        for (int p = 0; p < 3; ++p) {
            float4 v = xp[p * 64 + lane];
#pragma unroll
            for (int l = 0; l < LL; ++l) {
                acc[l] += v.x * wreg[p][0][l];
                acc[l] += v.y * wreg[p][1][l];
                acc[l] += v.z * wreg[p][2][l];
                acc[l] += v.w * wreg[p][3][l];
            }
        }
#pragma unroll
        for (int off = 32; off > 0; off >>= 1) {
#pragma unroll
            for (int l = 0; l < LL; ++l) acc[l] += __shfl_xor(acc[l], off, 64);
        }
        if (lane == 0) {
#pragma unroll
            for (int l = 0; l < LL; ++l)
                logits[(size_t)tok * LL + l] = acc[l] + breg[l];
        }
    }
}

// ---------------------------------------------------------------------------
// Kernel B: chunked semiring scans + score.
// Blocks 0..127: log-norm (lse semiring); 128..255: viterbi (max-plus);
// 256..383: sequence score (parallel over t). s_lg staged only for t < sl;
// stale LDS beyond is read-but-discarded through act? selects (bitwise-safe).
// ---------------------------------------------------------------------------
__global__ __launch_bounds__(256) void k_scan2(const float* __restrict__ logits,
                                               const int* __restrict__ label,
                                               const int* __restrict__ seqlen,
                                               const float* __restrict__ trans,
                                               float* __restrict__ lognorm,
                                               float* __restrict__ score,
                                               int* __restrict__ tags) {
    __shared__ float s_lg[TT * LL + 8];   // +pad: t=512 dummy reads
    __shared__ float s_P[32 * 25];
    __shared__ float s_A[33 * 5];
    __shared__ float s_tr[25];
    __shared__ float s_etr[25];
    __shared__ unsigned s_mapw[32];
    __shared__ int s_B[33];
    __shared__ int s_tags[TT];
    __shared__ float s_red[256];

    const int tid  = threadIdx.x;
    const int role = blockIdx.x >> 7;        // 0 = lognorm, 1 = viterbi, 2 = score
    const int n    = blockIdx.x & 127;
    const int sl   = seqlen[n & (BB - 1)];
    const float* lg = logits + (size_t)n * TT * LL;

    if (tid < 25) { const float tv = trans[tid]; s_tr[tid] = tv; s_etr[tid] = __expf(tv); }
    if (role < 2) {
        const int lim = sl * LL;             // only live logits
        for (int i = tid; i < lim; i += 256) s_lg[i] = lg[i];
    }
    __syncthreads();

    if (role == 0) {
        // ---------------- log-norm ----------------
        if (tid < 160) {
            const int c = tid / 5, r = tid - 5 * c;
            float p[5];
#pragma unroll
            for (int j = 0; j < 5; ++j) p[j] = (j == r) ? 0.f : NEG_INF;
#pragma unroll
            for (int i = 0; i < 16; ++i) {
                const int t = c * 16 + 1 + i;
                const bool act = t < sl;
                const float m = fmaxf(fmaxf(fmaxf(p[0], p[1]), fmaxf(p[2], p[3])), p[4]);
                float e[5];
#pragma unroll
                for (int k = 0; k < 5; ++k) e[k] = __expf(p[k] - m);
                float nv[5];
#pragma unroll
                for (int j = 0; j < 5; ++j) {
                    float s = e[0] * s_etr[j];
#pragma unroll
                    for (int k = 1; k < 5; ++k) s += e[k] * s_etr[k * 5 + j];
                    nv[j] = m + __logf(s) + s_lg[t * 5 + j];
                }
#pragma unroll
                for (int j = 0; j < 5; ++j) p[j] = act ? nv[j] : p[j];
            }
#pragma unroll
            for (int j = 0; j < 5; ++j) s_P[c * 25 + r * 5 + j] = __expf(p[j]);
        }
        __syncthreads();
        if (tid == 0) {
            float a[5];
#pragma unroll
            for (int j = 0; j < 5; ++j) a[j] = s_lg[j];
            for (int c = 0; c < 32; ++c) {
                const float m = fmaxf(fmaxf(fmaxf(a[0], a[1]), fmaxf(a[2], a[3])), a[4]);
                float e[5];
#pragma unroll
                for (int k = 0; k < 5; ++k) e[k] = __expf(a[k] - m);
                float nv[5];
#pragma unroll
                for (int j = 0; j < 5; ++j) {
                    float s = e[0] * s_P[c * 25 + j];
#pragma unroll
                    for (int k = 1; k < 5; ++k) s += e[k] * s_P[c * 25 + k * 5 + j];
                    nv[j] = m + __logf(s);
                }
#pragma unroll
                for (int j = 0; j < 5; ++j) a[j] = nv[j];
            }
            const float m = fmaxf(fmaxf(fmaxf(a[0], a[1]), fmaxf(a[2], a[3])), a[4]);
            float s = 0.f;
#pragma unroll
            for (int j = 0; j < 5; ++j) s += __expf(a[j] - m);
            lognorm[n] = m + __logf(s);
        }
    } else if (role == 1) {
        // ---------------- viterbi ----------------
        if (tid < 160) {
            const int c = tid / 5, r = tid - 5 * c;
            float p[5];
#pragma unroll
            for (int j = 0; j < 5; ++j) p[j] = (j == r) ? 0.f : NEG_INF;
#pragma unroll
            for (int i = 0; i < 16; ++i) {
                const int t = c * 16 + 1 + i;
                const bool act = t < sl;
                float nv[5];
#pragma unroll
                for (int j = 0; j < 5; ++j) {
                    float b = p[0] + s_tr[j];
#pragma unroll
                    for (int k = 1; k < 5; ++k) b = fmaxf(b, p[k] + s_tr[k * 5 + j]);
                    nv[j] = b + s_lg[t * 5 + j];
                }
#pragma unroll
                for (int j = 0; j < 5; ++j) p[j] = act ? nv[j] : p[j];
            }
#pragma unroll
            for (int j = 0; j < 5; ++j) s_P[c * 25 + r * 5 + j] = p[j];
        }
        __syncthreads();
        if (tid == 0) {                       // serial chunk-scan: boundary alphas
            float a[5];
#pragma unroll
            for (int j = 0; j < 5; ++j) { a[j] = s_lg[j]; s_A[j] = a[j]; }
            for (int c = 0; c < 32; ++c) {
                float nv[5];
#pragma unroll
                for (int j = 0; j < 5; ++j) {
                    float b = a[0] + s_P[c * 25 + j];
#pragma unroll
                    for (int k = 1; k < 5; ++k) b = fmaxf(b, a[k] + s_P[c * 25 + k * 5 + j]);
                    nv[j] = b;
                }
#pragma unroll
                for (int j = 0; j < 5; ++j) { a[j] = nv[j]; s_A[(c + 1) * 5 + j] = a[j]; }
            }
        }
        __syncthreads();
        unsigned bpw[16];                     // per-chunk backpointers, registers
        if (tid < 32) {
            const int c = tid;
            float a[5];
#pragma unroll
            for (int j = 0; j < 5; ++j) a[j] = s_A[c * 5 + j];
#pragma unroll
            for (int i = 0; i < 16; ++i) {
                const int t = c * 16 + 1 + i;
                const bool act = t < sl;
                float nv[5]; int gi[5];
#pragma unroll
                for (int j = 0; j < 5; ++j) {
                    float b = a[0] + s_tr[j]; int g = 0;
#pragma unroll
                    for (int k = 1; k < 5; ++k) {
                        const float cn = a[k] + s_tr[k * 5 + j];
                        if (cn > b) { b = cn; g = k; }
                    }
                    nv[j] = b + s_lg[t * 5 + j]; gi[j] = g;
                }
                const unsigned w = (unsigned)gi[0] | ((unsigned)gi[1] << 3) |
                                   ((unsigned)gi[2] << 6) | ((unsigned)gi[3] << 9) |
                                   ((unsigned)gi[4] << 12);
                bpw[i] = act ? w : IDENT_W;
#pragma unroll
                for (int j = 0; j < 5; ++j) a[j] = act ? nv[j] : a[j];
            }
            // compose chunk map (end-state -> start-state), pure VALU
            int m[5] = {0, 1, 2, 3, 4};
#pragma unroll
            for (int i = 15; i >= 0; --i) {
                const unsigned w = bpw[i];
#pragma unroll
                for (int j = 0; j < 5; ++j) m[j] = (int)((w >> (3 * m[j])) & 7u);
            }
            s_mapw[c] = (unsigned)m[0] | ((unsigned)m[1] << 3) | ((unsigned)m[2] << 6) |
                        ((unsigned)m[3] << 9) | ((unsigned)m[4] << 12);
        }
        __syncthreads();
        if (tid == 0) {                       // boundary tags via map chain (VALU)
            float b = s_A[32 * 5 + 0]; int lt = 0;
#pragma unroll
            for (int j = 1; j < 5; ++j) {
                const float cn = s_A[32 * 5 + j];
                if (cn > b) { b = cn; lt = j; }
            }
            unsigned w[32];
#pragma unroll
            for (int c = 0; c < 32; ++c) w[c] = s_mapw[c];
            int bc = lt; s_B[32] = lt;
#pragma unroll
            for (int c = 31; c >= 0; --c) { bc = (int)((w[c] >> (3 * bc)) & 7u); s_B[c] = bc; }
        }
        __syncthreads();
        if (tid < 32) {                       // emit tags from register bps
            int cur = s_B[tid + 1];
#pragma unroll
            for (int i = 15; i >= 0; --i) {
                cur = (int)((bpw[i] >> (3 * cur)) & 7u);
                s_tags[tid * 16 + i] = cur;
            }
        }
        __syncthreads();
        int* to = tags + n * TT;
        for (int i = tid; i < TT; i += 256) to[i] = s_tags[i];
    } else {
        // ---------------- sequence score ----------------
        const bool sec = (n >= BB);
        const int* lab = label + (n & (BB - 1)) * TT;
        float s = 0.f;
        for (int t = tid; t < TT; t += 256) {
            if (t < sl) {
                const int l = lab[t];
                const int tg = (l > 0) ? (sec ? l + 1 : 1) : 0;
                s += lg[t * LL + tg];
                if (t >= 1) {
                    const int lp = lab[t - 1];
                    const int tp = (lp > 0) ? (sec ? lp + 1 : 1) : 0;
                    s += s_tr[tp * LL + tg];
                }
            }
        }
        s_red[tid] = s;
        __syncthreads();
        for (int st = 128; st > 0; st >>= 1) {
            if (tid < st) s_red[tid] += s_red[tid + st];
            __syncthreads();
        }
        if (tid == 0) score[n] = s_red[0];
    }
}

// ---------------------------------------------------------------------------
// Kernel C: viterbi output + accuracy + loss, single block.
// ---------------------------------------------------------------------------
__global__ __launch_bounds__(1024) void k_tail(const int* __restrict__ tags,
                                               const int* __restrict__ label,
                                               const int* __restrict__ seqlen,
                                               const float* __restrict__ score,
                                               const float* __restrict__ lognorm,
                                               float* __restrict__ out) {
    __shared__ int s_ok[1024];
    __shared__ float s_f[1024];
    __shared__ int s_sl[1024];
    const int tid = threadIdx.x;
    int ok = 0;
    for (int i = tid; i < BB * TT; i += 1024) {
        const int bb = i >> 9, t = i & 511;
        const int v1 = tags[i];
        const int v2 = tags[i + BB * TT];
        const int vit = (v1 == 0 || v2 == 0) ? 0 : (v2 - 1);
        out[i] = (float)vit;
        ok += ((vit == label[i]) && (t < seqlen[bb])) ? 1 : 0;
    }
    s_ok[tid] = ok;
    s_f[tid]  = (tid < NSEQ) ? (lognorm[tid] - score[tid]) : 0.f;
    s_sl[tid] = (tid < BB) ? seqlen[tid] : 0;
    __syncthreads();
    for (int s = 512; s > 0; s >>= 1) {
        if (tid < s) { s_ok[tid] += s_ok[tid + s]; s_f[tid] += s_f[tid + s]; s_sl[tid] += s_sl[tid + s]; }
        __syncthreads();
    }
    if (tid == 0) {
        out[BB * TT]     = s_f[0] / (float)NSEQ;
        out[BB * TT + 1] = (float)s_ok[0] / (float)s_sl[0];
    }
}

// ---------------------------------------------------------------------------
extern "C" void kernel_launch(void* const* d_in, const int* in_sizes, int n_in,
                              void* d_out, int out_size, void* d_ws, size_t ws_size,
                              hipStream_t stream) {
    const float* x      = (const float*)d_in[0];
    const int*   label  = (const int*)d_in[1];
    const int*   seqlen = (const int*)d_in[2];
    const float* W      = (const float*)d_in[3];
    const float* bias   = (const float*)d_in[4];
    const float* trans  = (const float*)d_in[5];
    float* out = (float*)d_out;
    char*  ws  = (char*)d_ws;

    float* ws_logits  = (float*)(ws);                 // 1,310,720 B
    float* ws_score   = (float*)(ws + 1310720);       // 512 B
    float* ws_lognorm = (float*)(ws + 1311232);       // 512 B
    int*   ws_tags    = (int*)(ws + 1311744);         // 262,144 B

    hipLaunchKernelGGL(k_logits, dim3(2048), dim3(256), 0, stream,
                       x, W, bias, seqlen, ws_logits);
    hipLaunchKernelGGL(k_scan2, dim3(384), dim3(256), 0, stream,
                       ws_logits, label, seqlen, trans, ws_lognorm, ws_score, ws_tags);
    hipLaunchKernelGGL(k_tail, dim3(1), dim3(1024), 0, stream,
                       ws_tags, label, seqlen, ws_score, ws_lognorm, out);
}

// Round 6
// 62.102 us; speedup vs baseline: 1.7449x; 1.2003x over previous
//
#include <hip/hip_runtime.h>

#define BB 64
#define TT 512
#define DD 768
#define LL 5
#define NSEQ 128
#define NTOK 65536
#define NEG_INF (-1e30f)
#define IDENT_W 0x4688u   // bp word encoding j->j (0|1<<3|2<<6|3<<9|4<<12)

// ---------------------------------------------------------------------------
// Kernel A: logits = x @ W + b. Wave-per-token + seqlen skip. UNCHANGED from
// R5 (measured component for A/B attribution).
// ---------------------------------------------------------------------------
__global__ __launch_bounds__(256) void k_logits(const float* __restrict__ x,
                                                const float* __restrict__ W,
                                                const float* __restrict__ bias,
                                                const int* __restrict__ seqlen,
                                                float* __restrict__ logits) {
    const int lane = threadIdx.x & 63;
    const int wid  = blockIdx.x * (blockDim.x >> 6) + (threadIdx.x >> 6);
    const int nw   = gridDim.x * (blockDim.x >> 6);

    float wreg[3][4][LL];
#pragma unroll
    for (int p = 0; p < 3; ++p)
#pragma unroll
        for (int q = 0; q < 4; ++q) {
            const int d = p * 256 + lane * 4 + q;
#pragma unroll
            for (int l = 0; l < LL; ++l) wreg[p][q][l] = W[d * LL + l];
        }
    float breg[LL];
#pragma unroll
    for (int l = 0; l < LL; ++l) breg[l] = bias[l];

    for (int tok = wid; tok < NTOK; tok += nw) {
        const int t = tok & (TT - 1);
        const int n = tok >> 9;
        if (t >= seqlen[n & (BB - 1)]) continue;      // wave-uniform skip

        const float4* xp = reinterpret_cast<const float4*>(x + (size_t)tok * DD);
        float acc[LL] = {0.f, 0.f, 0.f, 0.f, 0.f};
#pragma unroll
        for (int p = 0; p < 3; ++p) {
            float4 v = xp[p * 64 + lane];
#pragma unroll
            for (int l = 0; l < LL; ++l) {
                acc[l] += v.x * wreg[p][0][l];
                acc[l] += v.y * wreg[p][1][l];
                acc[l] += v.z * wreg[p][2][l];
                acc[l] += v.w * wreg[p][3][l];
            }
        }
#pragma unroll
        for (int off = 32; off > 0; off >>= 1) {
#pragma unroll
            for (int l = 0; l < LL; ++l) acc[l] += __shfl_xor(acc[l], off, 64);
        }
        if (lane == 0) {
#pragma unroll
            for (int l = 0; l < LL; ++l)
                logits[(size_t)tok * LL + l] = acc[l] + breg[l];
        }
    }
}

// ---------------------------------------------------------------------------
// Kernel B: blocks 0..127 = log-norm (seq n); blocks 128..191 = viterbi PAIR
// (seq bb and bb+64; same seqlen) with fused viterbi output + ok counts (tags
// never leave LDS); blocks 192..319 = sequence score.
// ---------------------------------------------------------------------------
__global__ __launch_bounds__(256) void k_scan2(const float* __restrict__ logits,
                                               const int* __restrict__ label,
                                               const int* __restrict__ seqlen,
                                               const float* __restrict__ trans,
                                               float* __restrict__ lognorm,
                                               float* __restrict__ score,
                                               float* __restrict__ out,
                                               int* __restrict__ okpart) {
    __shared__ float s_lg[TT * LL + 8];
    __shared__ float s_P[32 * 25];
    __shared__ float s_A[33 * 5];
    __shared__ float s_tr[25];
    __shared__ float s_etr[25];
    __shared__ unsigned s_mapw[32];
    __shared__ int s_B[33];
    __shared__ int s_tags[2][TT];
    __shared__ float s_red[256];
    __shared__ int s_ok[256];

    const int tid = threadIdx.x;
    const int bid = blockIdx.x;

    if (tid < 25) { const float tv = trans[tid]; s_tr[tid] = tv; s_etr[tid] = __expf(tv); }

    if (bid < 128) {
        // ---------------- log-norm (seq n) ----------------
        const int n  = bid;
        const int sl = seqlen[n & (BB - 1)];
        const float* lg = logits + (size_t)n * TT * LL;
        const int lim = sl * LL;
        for (int i = tid; i < lim; i += 256) s_lg[i] = lg[i];
        __syncthreads();

        if (tid < 160) {
            const int c = tid / 5, r = tid - 5 * c;
            float p[5];
#pragma unroll
            for (int j = 0; j < 5; ++j) p[j] = (j == r) ? 0.f : NEG_INF;
#pragma unroll
            for (int i = 0; i < 16; ++i) {
                const int t = c * 16 + 1 + i;
                const bool act = t < sl;
                const float m = fmaxf(fmaxf(fmaxf(p[0], p[1]), fmaxf(p[2], p[3])), p[4]);
                float e[5];
#pragma unroll
                for (int k = 0; k < 5; ++k) e[k] = __expf(p[k] - m);
                float nv[5];
#pragma unroll
                for (int j = 0; j < 5; ++j) {
                    float s = e[0] * s_etr[j];
#pragma unroll
                    for (int k = 1; k < 5; ++k) s += e[k] * s_etr[k * 5 + j];
                    nv[j] = m + __logf(s) + s_lg[t * 5 + j];
                }
#pragma unroll
                for (int j = 0; j < 5; ++j) p[j] = act ? nv[j] : p[j];
            }
#pragma unroll
            for (int j = 0; j < 5; ++j) s_P[c * 25 + r * 5 + j] = __expf(p[j]);
        }
        __syncthreads();
        if (tid == 0) {
            float a[5];
#pragma unroll
            for (int j = 0; j < 5; ++j) a[j] = s_lg[j];
            for (int c = 0; c < 32; ++c) {
                const float m = fmaxf(fmaxf(fmaxf(a[0], a[1]), fmaxf(a[2], a[3])), a[4]);
                float e[5];
#pragma unroll
                for (int k = 0; k < 5; ++k) e[k] = __expf(a[k] - m);
                float nv[5];
#pragma unroll
                for (int j = 0; j < 5; ++j) {
                    float s = e[0] * s_P[c * 25 + j];
#pragma unroll
                    for (int k = 1; k < 5; ++k) s += e[k] * s_P[c * 25 + k * 5 + j];
                    nv[j] = m + __logf(s);
                }
#pragma unroll
                for (int j = 0; j < 5; ++j) a[j] = nv[j];
            }
            const float m = fmaxf(fmaxf(fmaxf(a[0], a[1]), fmaxf(a[2], a[3])), a[4]);
            float s = 0.f;
#pragma unroll
            for (int j = 0; j < 5; ++j) s += __expf(a[j] - m);
            lognorm[n] = m + __logf(s);
        }
    } else if (bid < 192) {
        // ---------------- viterbi pair (bb, bb+64) + combine ----------------
        const int bb = bid - 128;
        const int sl = seqlen[bb];
        for (int pass = 0; pass < 2; ++pass) {
            const int n = bb + pass * BB;
            const float* lg = logits + (size_t)n * TT * LL;
            const int lim = sl * LL;
            for (int i = tid; i < lim; i += 256) s_lg[i] = lg[i];
            __syncthreads();

            if (tid < 160) {
                const int c = tid / 5, r = tid - 5 * c;
                float p[5];
#pragma unroll
                for (int j = 0; j < 5; ++j) p[j] = (j == r) ? 0.f : NEG_INF;
#pragma unroll
                for (int i = 0; i < 16; ++i) {
                    const int t = c * 16 + 1 + i;
                    const bool act = t < sl;
                    float nv[5];
#pragma unroll
                    for (int j = 0; j < 5; ++j) {
                        float b = p[0] + s_tr[j];
#pragma unroll
                        for (int k = 1; k < 5; ++k) b = fmaxf(b, p[k] + s_tr[k * 5 + j]);
                        nv[j] = b + s_lg[t * 5 + j];
                    }
#pragma unroll
                    for (int j = 0; j < 5; ++j) p[j] = act ? nv[j] : p[j];
                }
#pragma unroll
                for (int j = 0; j < 5; ++j) s_P[c * 25 + r * 5 + j] = p[j];
            }
            __syncthreads();
            if (tid == 0) {                   // serial chunk-scan: boundary alphas
                float a[5];
#pragma unroll
                for (int j = 0; j < 5; ++j) { a[j] = s_lg[j]; s_A[j] = a[j]; }
                for (int c = 0; c < 32; ++c) {
                    float nv[5];
#pragma unroll
                    for (int j = 0; j < 5; ++j) {
                        float b = a[0] + s_P[c * 25 + j];
#pragma unroll
                        for (int k = 1; k < 5; ++k) b = fmaxf(b, a[k] + s_P[c * 25 + k * 5 + j]);
                        nv[j] = b;
                    }
#pragma unroll
                    for (int j = 0; j < 5; ++j) { a[j] = nv[j]; s_A[(c + 1) * 5 + j] = a[j]; }
                }
            }
            __syncthreads();
            unsigned bpw[16];
            if (tid < 32) {
                const int c = tid;
                float a[5];
#pragma unroll
                for (int j = 0; j < 5; ++j) a[j] = s_A[c * 5 + j];
#pragma unroll
                for (int i = 0; i < 16; ++i) {
                    const int t = c * 16 + 1 + i;
                    const bool act = t < sl;
                    float nv[5]; int gi[5];
#pragma unroll
                    for (int j = 0; j < 5; ++j) {
                        float b = a[0] + s_tr[j]; int g = 0;
#pragma unroll
                        for (int k = 1; k < 5; ++k) {
                            const float cn = a[k] + s_tr[k * 5 + j];
                            if (cn > b) { b = cn; g = k; }
                        }
                        nv[j] = b + s_lg[t * 5 + j]; gi[j] = g;
                    }
                    const unsigned w = (unsigned)gi[0] | ((unsigned)gi[1] << 3) |
                                       ((unsigned)gi[2] << 6) | ((unsigned)gi[3] << 9) |
                                       ((unsigned)gi[4] << 12);
                    bpw[i] = act ? w : IDENT_W;
#pragma unroll
                    for (int j = 0; j < 5; ++j) a[j] = act ? nv[j] : a[j];
                }
                int m[5] = {0, 1, 2, 3, 4};
#pragma unroll
                for (int i = 15; i >= 0; --i) {
                    const unsigned w = bpw[i];
#pragma unroll
                    for (int j = 0; j < 5; ++j) m[j] = (int)((w >> (3 * m[j])) & 7u);
                }
                s_mapw[tid] = (unsigned)m[0] | ((unsigned)m[1] << 3) | ((unsigned)m[2] << 6) |
                              ((unsigned)m[3] << 9) | ((unsigned)m[4] << 12);
            }
            __syncthreads();
            if (tid == 0) {                   // boundary tags via map chain
                float b = s_A[32 * 5 + 0]; int lt = 0;
#pragma unroll
                for (int j = 1; j < 5; ++j) {
                    const float cn = s_A[32 * 5 + j];
                    if (cn > b) { b = cn; lt = j; }
                }
                unsigned w[32];
#pragma unroll
                for (int c = 0; c < 32; ++c) w[c] = s_mapw[c];
                int bc = lt; s_B[32] = lt;
#pragma unroll
                for (int c = 31; c >= 0; --c) { bc = (int)((w[c] >> (3 * bc)) & 7u); s_B[c] = bc; }
            }
            __syncthreads();
            if (tid < 32) {
                int cur = s_B[tid + 1];
#pragma unroll
                for (int i = 15; i >= 0; --i) {
                    cur = (int)((bpw[i] >> (3 * cur)) & 7u);
                    s_tags[pass][tid * 16 + i] = cur;
                }
            }
            __syncthreads();
        }
        // fused combine: viterbi output + ok count (tags stay in LDS)
        const int* lab = label + bb * TT;
        int ok = 0;
        for (int t = tid; t < TT; t += 256) {
            const int t1 = s_tags[0][t];
            const int t2 = s_tags[1][t];
            const int vit = (t1 == 0 || t2 == 0) ? 0 : (t2 - 1);
            out[bb * TT + t] = (float)vit;
            ok += ((vit == lab[t]) && (t < sl)) ? 1 : 0;
        }
        s_ok[tid] = ok;
        __syncthreads();
        for (int s = 128; s > 0; s >>= 1) {
            if (tid < s) s_ok[tid] += s_ok[tid + s];
            __syncthreads();
        }
        if (tid == 0) okpart[bb] = s_ok[0];
    } else {
        // ---------------- sequence score (seq n) ----------------
        const int n  = bid - 192;
        const int sl = seqlen[n & (BB - 1)];
        const float* lg = logits + (size_t)n * TT * LL;
        const bool sec = (n >= BB);
        const int* lab = label + (n & (BB - 1)) * TT;
        __syncthreads();                      // s_tr ready
        float s = 0.f;
        for (int t = tid; t < TT; t += 256) {
            if (t < sl) {
                const int l = lab[t];
                const int tg = (l > 0) ? (sec ? l + 1 : 1) : 0;
                s += lg[t * LL + tg];
                if (t >= 1) {
                    const int lp = lab[t - 1];
                    const int tp = (lp > 0) ? (sec ? lp + 1 : 1) : 0;
                    s += s_tr[tp * LL + tg];
                }
            }
        }
        s_red[tid] = s;
        __syncthreads();
        for (int st = 128; st > 0; st >>= 1) {
            if (tid < st) s_red[tid] += s_red[tid + st];
            __syncthreads();
        }
        if (tid == 0) score[n] = s_red[0];
    }
}

// ---------------------------------------------------------------------------
// Kernel C: final scalars (loss, acc).
// ---------------------------------------------------------------------------
__global__ __launch_bounds__(128) void k_final(const float* __restrict__ score,
                                               const float* __restrict__ lognorm,
                                               const int* __restrict__ okpart,
                                               const int* __restrict__ seqlen,
                                               float* __restrict__ out) {
    __shared__ float sf[128];
    __shared__ int s1[128];
    __shared__ int s2[128];
    const int tid = threadIdx.x;
    sf[tid] = lognorm[tid] - score[tid];
    s1[tid] = (tid < BB) ? okpart[tid] : 0;
    s2[tid] = (tid < BB) ? seqlen[tid] : 0;
    __syncthreads();
    for (int s = 64; s > 0; s >>= 1) {
        if (tid < s) { sf[tid] += sf[tid + s]; s1[tid] += s1[tid + s]; s2[tid] += s2[tid + s]; }
        __syncthreads();
    }
    if (tid == 0) {
        out[BB * TT]     = sf[0] / (float)NSEQ;
        out[BB * TT + 1] = (float)s1[0] / (float)s2[0];
    }
}

// ---------------------------------------------------------------------------
extern "C" void kernel_launch(void* const* d_in, const int* in_sizes, int n_in,
                              void* d_out, int out_size, void* d_ws, size_t ws_size,
                              hipStream_t stream) {
    const float* x      = (const float*)d_in[0];
    const int*   label  = (const int*)d_in[1];
    const int*   seqlen = (const int*)d_in[2];
    const float* W      = (const float*)d_in[3];
    const float* bias   = (const float*)d_in[4];
    const float* trans  = (const float*)d_in[5];
    float* out = (float*)d_out;
    char*  ws  = (char*)d_ws;

    float* ws_logits  = (float*)(ws);                 // 1,310,720 B
    float* ws_score   = (float*)(ws + 1310720);       // 512 B
    float* ws_lognorm = (float*)(ws + 1311232);       // 512 B
    int*   ws_okpart  = (int*)(ws + 1311744);         // 256 B

    hipLaunchKernelGGL(k_logits, dim3(2048), dim3(256), 0, stream,
                       x, W, bias, seqlen, ws_logits);
    hipLaunchKernelGGL(k_scan2, dim3(320), dim3(256), 0, stream,
                       ws_logits, label, seqlen, trans, ws_lognorm, ws_score,
                       out, ws_okpart);
    hipLaunchKernelGGL(k_final, dim3(1), dim3(128), 0, stream,
                       ws_score, ws_lognorm, ws_okpart, seqlen, out);
}

// Round 8
// 53.053 us; speedup vs baseline: 2.0425x; 1.1706x over previous
//
#include <hip/hip_runtime.h>

#define BB 64
#define TT 512
#define DD 768
#define LL 5
#define NSEQ 128
#define NTOK 65536
#define NEG_INF (-1e30f)
#define IDENT_W 0x4688u   // bp word encoding j->j (0|1<<3|2<<6|3<<9|4<<12)

// ---------------------------------------------------------------------------
// Kernel A: logits = x @ W + b. Wave-per-token + seqlen skip. UNCHANGED from
// R5/R6 (measured ~HBM floor; A/B control).
// ---------------------------------------------------------------------------
__global__ __launch_bounds__(256) void k_logits(const float* __restrict__ x,
                                                const float* __restrict__ W,
                                                const float* __restrict__ bias,
                                                const int* __restrict__ seqlen,
                                                float* __restrict__ logits) {
    const int lane = threadIdx.x & 63;
    const int wid  = blockIdx.x * (blockDim.x >> 6) + (threadIdx.x >> 6);
    const int nw   = gridDim.x * (blockDim.x >> 6);

    float wreg[3][4][LL];
#pragma unroll
    for (int p = 0; p < 3; ++p)
#pragma unroll
        for (int q = 0; q < 4; ++q) {
            const int d = p * 256 + lane * 4 + q;
#pragma unroll
            for (int l = 0; l < LL; ++l) wreg[p][q][l] = W[d * LL + l];
        }
    float breg[LL];
#pragma unroll
    for (int l = 0; l < LL; ++l) breg[l] = bias[l];

    for (int tok = wid; tok < NTOK; tok += nw) {
        const int t = tok & (TT - 1);
        const int n = tok >> 9;
        if (t >= seqlen[n & (BB - 1)]) continue;      // wave-uniform skip

        const float4* xp = reinterpret_cast<const float4*>(x + (size_t)tok * DD);
        float acc[LL] = {0.f, 0.f, 0.f, 0.f, 0.f};
#pragma unroll
        for (int p = 0; p < 3; ++p) {
            float4 v = xp[p * 64 + lane];
#pragma unroll
            for (int l = 0; l < LL; ++l) {
                acc[l] += v.x * wreg[p][0][l];
                acc[l] += v.y * wreg[p][1][l];
                acc[l] += v.z * wreg[p][2][l];
                acc[l] += v.w * wreg[p][3][l];
            }
        }
#pragma unroll
        for (int off = 32; off > 0; off >>= 1) {
#pragma unroll
            for (int l = 0; l < LL; ++l) acc[l] += __shfl_xor(acc[l], off, 64);
        }
        if (lane == 0) {
#pragma unroll
            for (int l = 0; l < LL; ++l)
                logits[(size_t)tok * LL + l] = acc[l] + breg[l];
        }
    }
}

// ---------------------------------------------------------------------------
// Kernel B: ONE block per sequence pair (bb, bb+64); 512 threads. All phases
// log-depth parallel: lse-matmul tree for lognorm, Kogge-Stone max-plus scan
// for viterbi, parallel bp re-scan + backtrace, fused combine/score/ok.
// ---------------------------------------------------------------------------
__global__ __launch_bounds__(512) void k_scan3(const float* __restrict__ logits,
                                               const int* __restrict__ label,
                                               const int* __restrict__ seqlen,
                                               const float* __restrict__ trans,
                                               float* __restrict__ out,
                                               float* __restrict__ losspart,
                                               int* __restrict__ okpart) {
    __shared__ float s_lg[2][TT * LL + 8];   // +pad: t=512 dummy reads
    __shared__ float s_P[2 * 800];           // 32 mats of 25 per seq
    __shared__ float s_Q[2 * 400];           // 16 mats of 25 per seq (ping-pong)
    __shared__ float s_A[2][33 * 5];
    __shared__ float s_tr[25];
    __shared__ float s_etr[25];
    __shared__ unsigned s_mapw[2][32];
    __shared__ int s_B[2][33];
    __shared__ int s_tags[2][TT];
    __shared__ float s_ln[2];
    __shared__ int s_wok[8];
    __shared__ float s_wa[8], s_wb[8];

    const int tid = threadIdx.x;
    const int bb  = blockIdx.x;              // 0..63
    const int sl  = seqlen[bb];
    const float* lgA = logits + (size_t)bb * TT * LL;
    const float* lgB = logits + (size_t)(bb + BB) * TT * LL;

    // ---- P1: stage ----
    if (tid < 25) { const float tv = trans[tid]; s_tr[tid] = tv; s_etr[tid] = __expf(tv); }
    {
        const int lim = sl * LL;
        for (int i = tid; i < lim; i += 512) { s_lg[0][i] = lgA[i]; s_lg[1][i] = lgB[i]; }
    }
    __syncthreads();

    // decode for 320-thread phases
    const int sid = tid / 160;               // seq (valid when tid<320)
    const int rem = tid - sid * 160;
    const int cc  = rem / 5;
    const int rr  = rem - cc * 5;

    // ---- P2: lognorm chunk matrices (log domain) ----
    if (tid < 320) {
        float p[5];
#pragma unroll
        for (int j = 0; j < 5; ++j) p[j] = (j == rr) ? 0.f : NEG_INF;
#pragma unroll
        for (int i = 0; i < 16; ++i) {
            const int t = cc * 16 + 1 + i;
            const bool act = t < sl;
            const float m = fmaxf(fmaxf(fmaxf(p[0], p[1]), fmaxf(p[2], p[3])), p[4]);
            float e[5];
#pragma unroll
            for (int k = 0; k < 5; ++k) e[k] = __expf(p[k] - m);
            float nv[5];
#pragma unroll
            for (int j = 0; j < 5; ++j) {
                float s = e[0] * s_etr[j];
#pragma unroll
                for (int k = 1; k < 5; ++k) s += e[k] * s_etr[k * 5 + j];
                nv[j] = m + __logf(s) + s_lg[sid][t * 5 + j];
            }
#pragma unroll
            for (int j = 0; j < 5; ++j) p[j] = act ? nv[j] : p[j];
        }
#pragma unroll
        for (int j = 0; j < 5; ++j) s_P[sid * 800 + cc * 25 + rr * 5 + j] = p[j];
    }
    __syncthreads();

    // ---- P3: lse-matmul tree reduction 32 -> 1 (5 levels, ping-pong) ----
    {
        const float* inb; float* outb; int ist, ost;
#pragma unroll
        for (int lev = 0; lev < 5; ++lev) {
            const int np = 16 >> lev;        // outputs per seq this level
            if (lev & 1) { inb = s_Q; ist = 400; outb = s_P; ost = 800; }
            else         { inb = s_P; ist = 800; outb = s_Q; ost = 400; }
            const int total = 2 * np * 25;
            for (int task = tid; task < total; task += 512) {
                const int s  = task / (np * 25);
                const int r2 = task - s * (np * 25);
                const int p  = r2 / 25;
                const int e  = r2 - p * 25;
                const int r  = e / 5, j = e - 5 * r;
                const float* A  = inb + s * ist + (2 * p) * 25;
                const float* Bm = inb + s * ist + (2 * p + 1) * 25;
                float v[5];
#pragma unroll
                for (int k = 0; k < 5; ++k) v[k] = A[r * 5 + k] + Bm[k * 5 + j];
                float m = fmaxf(fmaxf(fmaxf(v[0], v[1]), fmaxf(v[2], v[3])), v[4]);
                float ssum = 0.f;
#pragma unroll
                for (int k = 0; k < 5; ++k) ssum += __expf(v[k] - m);
                outb[s * ost + p * 25 + e] = m + __logf(ssum);
            }
            __syncthreads();
        }
    }
    // result: s_Q[s*400 + 0..24]

    // ---- P4+P5: lognorm finalize (2 spare threads) || viterbi chunk mats ----
    if (tid >= 508 && tid < 510) {
        const int s = tid - 508;
        const float* M = s_Q + s * 400;
        float b[5];
#pragma unroll
        for (int j = 0; j < 5; ++j) {
            float v[5];
#pragma unroll
            for (int k = 0; k < 5; ++k) v[k] = s_lg[s][k] + M[k * 5 + j];
            float m = fmaxf(fmaxf(fmaxf(v[0], v[1]), fmaxf(v[2], v[3])), v[4]);
            float ssum = 0.f;
#pragma unroll
            for (int k = 0; k < 5; ++k) ssum += __expf(v[k] - m);
            b[j] = m + __logf(ssum);
        }
        float m = fmaxf(fmaxf(fmaxf(b[0], b[1]), fmaxf(b[2], b[3])), b[4]);
        float ssum = 0.f;
#pragma unroll
        for (int j = 0; j < 5; ++j) ssum += __expf(b[j] - m);
        s_ln[s] = m + __logf(ssum);
    }
    if (tid < 320) {
        float p[5];
#pragma unroll
        for (int j = 0; j < 5; ++j) p[j] = (j == rr) ? 0.f : NEG_INF;
#pragma unroll
        for (int i = 0; i < 16; ++i) {
            const int t = cc * 16 + 1 + i;
            const bool act = t < sl;
            float nv[5];
#pragma unroll
            for (int j = 0; j < 5; ++j) {
                float b = p[0] + s_tr[j];
#pragma unroll
                for (int k = 1; k < 5; ++k) b = fmaxf(b, p[k] + s_tr[k * 5 + j]);
                nv[j] = b + s_lg[sid][t * 5 + j];
            }
#pragma unroll
            for (int j = 0; j < 5; ++j) p[j] = act ? nv[j] : p[j];
        }
#pragma unroll
        for (int j = 0; j < 5; ++j) s_P[sid * 800 + cc * 25 + rr * 5 + j] = p[j];
    }
    __syncthreads();

    // ---- P6: Kogge-Stone max-plus inclusive scan over 32 chunk matrices ----
#pragma unroll
    for (int st = 1; st < 32; st <<= 1) {
        float Ar[5], Bm[25];
        const bool doit = (tid < 320) && (cc >= st);
        if (doit) {
#pragma unroll
            for (int k = 0; k < 5; ++k) Ar[k] = s_P[sid * 800 + (cc - st) * 25 + rr * 5 + k];
#pragma unroll
            for (int e = 0; e < 25; ++e) Bm[e] = s_P[sid * 800 + cc * 25 + e];
        }
        __syncthreads();
        if (doit) {
#pragma unroll
            for (int j = 0; j < 5; ++j) {
                float b = Ar[0] + Bm[j];
#pragma unroll
                for (int k = 1; k < 5; ++k) b = fmaxf(b, Ar[k] + Bm[k * 5 + j]);
                s_P[sid * 800 + cc * 25 + rr * 5 + j] = b;
            }
        }
        __syncthreads();
    }

    // ---- P7: boundary alphas ----
    if (tid < 320) {
        // here decode (s, c, j): reuse sid, cc, and rr as j
        float b = s_lg[sid][0] + s_P[sid * 800 + cc * 25 + rr];
#pragma unroll
        for (int k = 1; k < 5; ++k)
            b = fmaxf(b, s_lg[sid][k] + s_P[sid * 800 + cc * 25 + k * 5 + rr]);
        s_A[sid][(cc + 1) * 5 + rr] = b;
    } else if (tid < 330) {
        const int i2 = tid - 320;
        const int s = i2 / 5, j = i2 - 5 * s;
        s_A[s][j] = s_lg[s][j];
    }
    __syncthreads();

    // ---- P8: bp re-scan (64 threads, bpw in registers) ----
    unsigned bpw[16];
    const int vs = tid >> 5, vc = tid & 31;  // valid when tid<64
    if (tid < 64) {
        float a[5];
#pragma unroll
        for (int j = 0; j < 5; ++j) a[j] = s_A[vs][vc * 5 + j];
#pragma unroll
        for (int i = 0; i < 16; ++i) {
            const int t = vc * 16 + 1 + i;
            const bool act = t < sl;
            float nv[5]; int gi[5];
#pragma unroll
            for (int j = 0; j < 5; ++j) {
                float b = a[0] + s_tr[j]; int g = 0;
#pragma unroll
                for (int k = 1; k < 5; ++k) {
                    const float cn = a[k] + s_tr[k * 5 + j];
                    if (cn > b) { b = cn; g = k; }
                }
                nv[j] = b + s_lg[vs][t * 5 + j]; gi[j] = g;
            }
            const unsigned w = (unsigned)gi[0] | ((unsigned)gi[1] << 3) |
                               ((unsigned)gi[2] << 6) | ((unsigned)gi[3] << 9) |
                               ((unsigned)gi[4] << 12);
            bpw[i] = act ? w : IDENT_W;
#pragma unroll
            for (int j = 0; j < 5; ++j) a[j] = act ? nv[j] : a[j];
        }
        int m[5] = {0, 1, 2, 3, 4};
#pragma unroll
        for (int i = 15; i >= 0; --i) {
            const unsigned w = bpw[i];
#pragma unroll
            for (int j = 0; j < 5; ++j) m[j] = (int)((w >> (3 * m[j])) & 7u);
        }
        s_mapw[vs][vc] = (unsigned)m[0] | ((unsigned)m[1] << 3) | ((unsigned)m[2] << 6) |
                         ((unsigned)m[3] << 9) | ((unsigned)m[4] << 12);
    }
    __syncthreads();

    // ---- P9: boundary tag chains (2 threads) ----
    if (tid < 2) {
        const int s = tid;
        float b = s_A[s][32 * 5 + 0]; int lt = 0;
#pragma unroll
        for (int j = 1; j < 5; ++j) {
            const float cn = s_A[s][32 * 5 + j];
            if (cn > b) { b = cn; lt = j; }
        }
        unsigned w[32];
#pragma unroll
        for (int c = 0; c < 32; ++c) w[c] = s_mapw[s][c];
        int bc = lt; s_B[s][32] = lt;
#pragma unroll
        for (int c = 31; c >= 0; --c) { bc = (int)((w[c] >> (3 * bc)) & 7u); s_B[s][c] = bc; }
    }
    __syncthreads();

    // ---- P10: emit tags ----
    if (tid < 64) {
        int cur = s_B[vs][vc + 1];
#pragma unroll
        for (int i = 15; i >= 0; --i) {
            cur = (int)((bpw[i] >> (3 * cur)) & 7u);
            s_tags[vs][vc * 16 + i] = cur;
        }
    }
    __syncthreads();

    // ---- P11: combine + score + reduce ----
    {
        const int t = tid;                   // 0..511 == TT
        const int* lab = label + bb * TT;
        const int t1 = s_tags[0][t];
        const int t2 = s_tags[1][t];
        const int vit = (t1 == 0 || t2 == 0) ? 0 : (t2 - 1);
        out[bb * TT + t] = (float)vit;
        const int lv = lab[t];
        int ok = ((vit == lv) && (t < sl)) ? 1 : 0;
        float scA = 0.f, scB = 0.f;
        if (t < sl) {
            const int tgA = (lv > 0) ? 1 : 0;
            const int tgB = (lv > 0) ? lv + 1 : 0;
            scA = s_lg[0][t * 5 + tgA];
            scB = s_lg[1][t * 5 + tgB];
            if (t >= 1) {
                const int lp = lab[t - 1];
                const int tpA = (lp > 0) ? 1 : 0;
                const int tpB = (lp > 0) ? lp + 1 : 0;
                scA += s_tr[tpA * 5 + tgA];
                scB += s_tr[tpB * 5 + tgB];
            }
        }
#pragma unroll
        for (int off = 32; off > 0; off >>= 1) {
            ok  += __shfl_xor(ok, off, 64);
            scA += __shfl_xor(scA, off, 64);
            scB += __shfl_xor(scB, off, 64);
        }
        if ((tid & 63) == 0) { s_wok[tid >> 6] = ok; s_wa[tid >> 6] = scA; s_wb[tid >> 6] = scB; }
    }
    __syncthreads();
    if (tid == 0) {
        int ok = 0; float sA = 0.f, sB = 0.f;
#pragma unroll
        for (int w = 0; w < 8; ++w) { ok += s_wok[w]; sA += s_wa[w]; sB += s_wb[w]; }
        okpart[bb]   = ok;
        losspart[bb] = (s_ln[0] - sA) + (s_ln[1] - sB);
    }
}

// ---------------------------------------------------------------------------
// Kernel C: final scalars (1 wave).
// ---------------------------------------------------------------------------
__global__ __launch_bounds__(64) void k_final(const float* __restrict__ losspart,
                                              const int* __restrict__ okpart,
                                              const int* __restrict__ seqlen,
                                              float* __restrict__ out) {
    const int tid = threadIdx.x;
    float f = losspart[tid];
    int ok = okpart[tid];
    int sl = seqlen[tid];
#pragma unroll
    for (int off = 32; off > 0; off >>= 1) {
        f  += __shfl_xor(f, off, 64);
        ok += __shfl_xor(ok, off, 64);
        sl += __shfl_xor(sl, off, 64);
    }
    if (tid == 0) {
        out[BB * TT]     = f / (float)NSEQ;
        out[BB * TT + 1] = (float)ok / (float)sl;
    }
}

// ---------------------------------------------------------------------------
extern "C" void kernel_launch(void* const* d_in, const int* in_sizes, int n_in,
                              void* d_out, int out_size, void* d_ws, size_t ws_size,
                              hipStream_t stream) {
    const float* x      = (const float*)d_in[0];
    const int*   label  = (const int*)d_in[1];
    const int*   seqlen = (const int*)d_in[2];
    const float* W      = (const float*)d_in[3];
    const float* bias   = (const float*)d_in[4];
    const float* trans  = (const float*)d_in[5];
    float* out = (float*)d_out;
    char*  ws  = (char*)d_ws;

    float* ws_logits   = (float*)(ws);                // 1,310,720 B
    float* ws_losspart = (float*)(ws + 1310720);      // 256 B
    int*   ws_okpart   = (int*)(ws + 1310976);        // 256 B

    hipLaunchKernelGGL(k_logits, dim3(2048), dim3(256), 0, stream,
                       x, W, bias, seqlen, ws_logits);
    hipLaunchKernelGGL(k_scan3, dim3(64), dim3(512), 0, stream,
                       ws_logits, label, seqlen, trans, out, ws_losspart, ws_okpart);
    hipLaunchKernelGGL(k_final, dim3(1), dim3(64), 0, stream,
                       ws_losspart, ws_okpart, seqlen, out);
}